// Round 2
// baseline (15754.898 us; speedup 1.0000x reference)
//
#include <hip/hip_runtime.h>
#include <hip/hip_bf16.h>

#define TT 127

typedef __attribute__((ext_vector_type(8))) short s8v;
typedef __attribute__((ext_vector_type(4))) float f4v;

__device__ __forceinline__ float bf2f(unsigned short u){
  union { unsigned int i; float f; } v; v.i = ((unsigned int)u) << 16; return v.f;
}
__device__ __forceinline__ unsigned short f2bf(float f){
  union { float f; unsigned int i; } v; v.f = f;
  unsigned int r = v.i + 0x7FFFu + ((v.i >> 16) & 1u);
  return (unsigned short)(r >> 16);
}
__device__ __forceinline__ float fexp2(float x){ return __builtin_amdgcn_exp2f(x); }
__device__ __forceinline__ float frcp(float x){ return __builtin_amdgcn_rcpf(x); }
__device__ __forceinline__ float sigm(float x){
  return frcp(1.f + fexp2(-1.4426950408889634f * x));
}
__device__ __forceinline__ float tanh_f(float x){
  return 1.f - 2.f * frcp(1.f + fexp2(2.8853900817779268f * x));
}
__device__ __forceinline__ f4v mfma16(s8v a, s8v b, f4v c){
  return __builtin_amdgcn_mfma_f32_16x16x32_bf16(a, b, c, 0, 0, 0);
}

// ---------- prep: pack Whh into per-wave MFMA B-fragments (bf16) ----------
// WhhP[w][f][lane][8], w=0..15, f=ct*8+kt (ct=0..3, kt=0..7)
// B[k=i][n=g] = Whh[g][i]; g=(w*4+ct)*16+(lane&15), i=kt*32+(lane>>4)*8+j
__global__ void k_pack_whh(const float* __restrict__ Whh, unsigned short* __restrict__ WhhP){
  int idx = blockIdx.x * 256 + threadIdx.x;   // 32768
  int lane = idx & 63;
  int f = (idx >> 6) & 31;
  int w = idx >> 11;
  int ct = f >> 3, kt = f & 7;
  int g = (w * 4 + ct) * 16 + (lane & 15);
  int i0 = kt * 32 + (lane >> 4) * 8;
  #pragma unroll
  for (int j = 0; j < 8; ++j)
    WhhP[idx * 8 + j] = f2bf(Whh[g * 256 + i0 + j]);
}

// W1dcP[w][kt][lane][8], kt=0..15; B[k=i][n=h] = W1[h][i], h=w*16+(lane&15), i=kt*32+(lane>>4)*8+j (<512)
__global__ void k_pack_w1dc(const float* __restrict__ W1, unsigned short* __restrict__ W1dcP){
  int idx = blockIdx.x * 256 + threadIdx.x;   // 16384
  int lane = idx & 63;
  int kt = (idx >> 6) & 15;
  int w = idx >> 10;
  int h = w * 16 + (lane & 15);
  int i0 = kt * 32 + (lane >> 4) * 8;
  #pragma unroll
  for (int j = 0; j < 8; ++j)
    W1dcP[idx * 8 + j] = f2bf(W1[h * 768 + i0 + j]);
}

__global__ void k_tr_w1x(const float* __restrict__ W1, float* __restrict__ W1xT){
  int idx = blockIdx.x * 256 + threadIdx.x;   // 256*256
  int k = idx >> 8, h = idx & 255;
  W1xT[idx] = W1[h * 768 + 512 + k];
}

__global__ void k_xbf(const float* __restrict__ X, unsigned short* __restrict__ Xbf){
  int idx = blockIdx.x * 256 + threadIdx.x;   // quads: 8323072
  float4 v = ((const float4*)X)[idx];
  ushort4 o;
  o.x = f2bf(v.x); o.y = f2bf(v.y); o.z = f2bf(v.z); o.w = f2bf(v.w);
  ((ushort4*)Xbf)[idx] = o;
}

// ---------- prep: Tx[b,t,h] = tanh( X[b,t,:]·W1x[h,:] + b1[h] ), bf16 ----------
__global__ __launch_bounds__(256) void k_gemm_tx(
    const float* __restrict__ X, const float* __restrict__ W1xT,
    const float* __restrict__ b1, unsigned short* __restrict__ Tx)
{
  __shared__ float As[16][64];
  __shared__ float Bs[16][64];
  const int row0 = blockIdx.x * 64;
  const int col0 = blockIdx.y * 64;
  const int tid = threadIdx.x;
  const int tx = tid & 15, ty = tid >> 4;
  float acc[4][4] = {};
  for (int k0 = 0; k0 < 256; k0 += 16) {
    {
      const int rr = tid & 63, kk4 = (tid >> 6) << 2;
      float4 v = *(const float4*)&X[(size_t)(row0 + rr) * 256 + k0 + kk4];
      As[kk4 + 0][rr] = v.x; As[kk4 + 1][rr] = v.y;
      As[kk4 + 2][rr] = v.z; As[kk4 + 3][rr] = v.w;
    }
    {
      const int cc = tid & 63, kb = tid >> 6;
      #pragma unroll
      for (int j = 0; j < 4; ++j)
        Bs[kb + 4 * j][cc] = W1xT[(size_t)(k0 + kb + 4 * j) * 256 + col0 + cc];
    }
    __syncthreads();
    #pragma unroll
    for (int kk = 0; kk < 16; ++kk) {
      float4 a4 = *(const float4*)&As[kk][ty << 2];
      float4 b4 = *(const float4*)&Bs[kk][tx << 2];
      float av[4] = {a4.x, a4.y, a4.z, a4.w};
      float bv[4] = {b4.x, b4.y, b4.z, b4.w};
      #pragma unroll
      for (int i = 0; i < 4; ++i)
        #pragma unroll
        for (int j = 0; j < 4; ++j)
          acc[i][j] = fmaf(av[i], bv[j], acc[i][j]);
    }
    __syncthreads();
  }
  const int c = col0 + (tx << 2);
  #pragma unroll
  for (int i = 0; i < 4; ++i) {
    const int r = row0 + (ty << 2) + i;
    ushort4 o;
    o.x = f2bf(tanhf(acc[i][0] + b1[c + 0]));
    o.y = f2bf(tanhf(acc[i][1] + b1[c + 1]));
    o.z = f2bf(tanhf(acc[i][2] + b1[c + 2]));
    o.w = f2bf(tanhf(acc[i][3] + b1[c + 3]));
    *(ushort4*)&Tx[(size_t)r * 256 + c] = o;
  }
}

// ---------- main ----------
template<int USE_XBF>
__global__ __launch_bounds__(1024, 4) void k_main(
    const float* __restrict__ X,
    const unsigned short* __restrict__ Tx,
    const unsigned short* __restrict__ Xbf,
    const unsigned short* __restrict__ WhhP,
    const unsigned short* __restrict__ W1dcP,
    const float* __restrict__ yprev,
    const float* __restrict__ W2,
    const float* __restrict__ Wih,
    const float* __restrict__ bih,
    const float* __restrict__ bhh,
    const float* __restrict__ fcW,
    const float* __restrict__ fcb,
    const float* __restrict__ fcfW,
    const float* __restrict__ fcfb,
    float* __restrict__ out)
{
  __shared__ __align__(16) unsigned short dcA_hi[4][520];
  __shared__ __align__(16) unsigned short dcA_lo[4][520];
  __shared__ __align__(16) float us_s[4][256];
  __shared__ __align__(16) float wtu_s[4][256];
  __shared__ __align__(16) float sc[4][128];
  __shared__ __align__(16) float ctx[4][256];
  __shared__ __align__(16) float gts[4][1024];
  __shared__ float w2s[256];
  __shared__ float fcw_s[257];
  __shared__ float fcfw_s[512];
  __shared__ float wih_s[1024];
  __shared__ float bsum_s[1024];
  __shared__ float ytil[4];

  const int tid = threadIdx.x;
  const int lane = tid & 63;
  const int w = tid >> 6;          // wave 0..15
  const int bb = tid >> 8;         // 0..3
  const int hq = tid & 255;        // 0..255
  const int b0 = blockIdx.x << 2;

  // ---- load weight fragments into registers (once) ----
  s8v whb[32];
  #pragma unroll
  for (int f = 0; f < 32; ++f)
    whb[f] = *(const s8v*)&WhhP[((size_t)(w * 32 + f) * 64 + lane) * 8];
  s8v w1b[16];
  #pragma unroll
  for (int f = 0; f < 16; ++f)
    w1b[f] = *(const s8v*)&W1dcP[((size_t)(w * 16 + f) * 64 + lane) * 8];

  // phase-B static per-lane W2 slice
  float w2r[16];
  {
    const int cc0 = lane & 15;
    #pragma unroll
    for (int e4 = 0; e4 < 4; ++e4) {
      f4v v = *(const f4v*)&W2[cc0 * 16 + e4 * 4];
      w2r[e4*4+0] = v[0]; w2r[e4*4+1] = v[1]; w2r[e4*4+2] = v[2]; w2r[e4*4+3] = v[3];
    }
  }

  if (tid < 256) w2s[tid] = W2[tid];
  if (tid < 257) fcw_s[tid] = fcW[tid];
  if (tid < 512) fcfw_s[tid] = fcfW[tid];
  wih_s[tid] = Wih[tid];
  bsum_s[tid] = bih[tid] + bhh[tid];
  for (int i = tid; i < 4 * 520; i += 1024) {
    (&dcA_hi[0][0])[i] = 0;
    (&dcA_lo[0][0])[i] = 0;
  }
  float creg = 0.f, dreg = 0.f;
  __syncthreads();

  const int arow = lane & 15;
  const int koff = (lane >> 4) << 4;   // byte offset: (lane>>4)*8 elems * 2B

  for (int t = 0; t < TT; ++t) {
    // ================= A: MFMA  u = [d,c]·W1dc^T ; ghh = d·Whh^T =================
    {
      s8v ah[8], al[8];
      #pragma unroll
      for (int kt = 0; kt < 8; ++kt) {
        s8v hv = (s8v)0, lv = (s8v)0;
        if (arow < 4) {
          const char* bh = (const char*)&dcA_hi[0][0] + arow * 1040 + kt * 64 + koff;
          const char* bl = (const char*)&dcA_lo[0][0] + arow * 1040 + kt * 64 + koff;
          hv = *(const s8v*)bh;
          lv = *(const s8v*)bl;
        }
        ah[kt] = hv; al[kt] = lv;
      }
      f4v au = {0.f, 0.f, 0.f, 0.f};
      #pragma unroll
      for (int kt = 0; kt < 8; ++kt) {
        au = mfma16(ah[kt], w1b[kt], au);
        au = mfma16(al[kt], w1b[kt], au);
      }
      #pragma unroll
      for (int kt = 8; kt < 16; ++kt) {
        s8v hv = (s8v)0, lv = (s8v)0;
        if (arow < 4) {
          const char* bh = (const char*)&dcA_hi[0][0] + arow * 1040 + kt * 64 + koff;
          const char* bl = (const char*)&dcA_lo[0][0] + arow * 1040 + kt * 64 + koff;
          hv = *(const s8v*)bh;
          lv = *(const s8v*)bl;
        }
        au = mfma16(hv, w1b[kt], au);
        au = mfma16(lv, w1b[kt], au);
      }
      f4v ag[4];
      #pragma unroll
      for (int ct = 0; ct < 4; ++ct) ag[ct] = (f4v){0.f, 0.f, 0.f, 0.f};
      #pragma unroll
      for (int ct = 0; ct < 4; ++ct) {
        #pragma unroll
        for (int kt = 0; kt < 8; ++kt) {
          ag[ct] = mfma16(ah[kt], whb[ct * 8 + kt], ag[ct]);
          ag[ct] = mfma16(al[kt], whb[ct * 8 + kt], ag[ct]);
        }
      }
      // epilogue: lanes 0..15 hold rows 0..3 in regs 0..3
      if (lane < 16) {
        const int h = w * 16 + lane;
        const float w2v = w2s[h];
        #pragma unroll
        for (int r = 0; r < 4; ++r) {
          const float tu = tanh_f(au[r]);
          us_s[r][h] = tu;
          wtu_s[r][h] = w2v * tu;
        }
        #pragma unroll
        for (int ct = 0; ct < 4; ++ct) {
          const int g0 = (w * 4 + ct) * 16 + lane;
          #pragma unroll
          for (int r = 0; r < 4; ++r)
            gts[r][g0] = ag[ct][r];
        }
      }
    }
    __syncthreads();

    // ================= B: scores via tanh addition formula =================
    {
      const int bq = w >> 2;
      const int cc = lane & 15;
      const int g4 = lane >> 4;
      float tur[16], wtur[16];
      #pragma unroll
      for (int e4 = 0; e4 < 4; ++e4) {
        f4v tv = *(const f4v*)&us_s[bq][cc * 16 + e4 * 4];
        f4v wv = *(const f4v*)&wtu_s[bq][cc * 16 + e4 * 4];
        tur[e4*4+0] = tv[0]; tur[e4*4+1] = tv[1]; tur[e4*4+2] = tv[2]; tur[e4*4+3] = tv[3];
        wtur[e4*4+0] = wv[0]; wtur[e4*4+1] = wv[1]; wtur[e4*4+2] = wv[2]; wtur[e4*4+3] = wv[3];
      }
      const unsigned short* txb = &Tx[((size_t)(b0 + bq) * TT) * 256 + cc * 16];
      #pragma unroll 4
      for (int it = 0; it < 8; ++it) {
        const int tt = it * 16 + (w & 3) * 4 + g4;
        const int ttc = tt < 126 ? tt : 126;
        const unsigned short* p = txb + (size_t)ttc * 256;
        s8v xa = *(const s8v*)p;
        s8v xb = *(const s8v*)(p + 8);
        float acc = 0.f;
        #pragma unroll
        for (int e = 0; e < 8; ++e) {
          const float x = bf2f((unsigned short)xa[e]);
          const float den = fmaf(tur[e], x, 1.f);
          const float num = fmaf(w2r[e], x, wtur[e]);
          acc = fmaf(num, frcp(den), acc);
        }
        #pragma unroll
        for (int e = 0; e < 8; ++e) {
          const float x = bf2f((unsigned short)xb[e]);
          const float den = fmaf(tur[8 + e], x, 1.f);
          const float num = fmaf(w2r[8 + e], x, wtur[8 + e]);
          acc = fmaf(num, frcp(den), acc);
        }
        acc += __shfl_xor(acc, 1);
        acc += __shfl_xor(acc, 2);
        acc += __shfl_xor(acc, 4);
        acc += __shfl_xor(acc, 8);
        if (cc == 0 && tt < TT) sc[bq][tt] = acc;
      }
    }
    __syncthreads();

    // ================= softmax (waves 0..3) =================
    if (w < 4) {
      const float s0 = sc[w][lane];
      const float s1 = (lane < 63) ? sc[w][lane + 64] : -3.0e38f;
      float mx = fmaxf(s0, s1);
      #pragma unroll
      for (int m = 32; m; m >>= 1) mx = fmaxf(mx, __shfl_xor(mx, m));
      const float p0 = fexp2((s0 - mx) * 1.4426950408889634f);
      const float p1 = (lane < 63) ? fexp2((s1 - mx) * 1.4426950408889634f) : 0.f;
      float sm = p0 + p1;
      #pragma unroll
      for (int m = 32; m; m >>= 1) sm += __shfl_xor(sm, m);
      const float inv = frcp(sm);
      sc[w][lane] = p0 * inv;
      if (lane < 63) sc[w][lane + 64] = p1 * inv;
    }
    __syncthreads();

    // ================= C: context =================
    {
      float acc = 0.f;
      if constexpr (USE_XBF) {
        const unsigned short* xp = &Xbf[((size_t)(b0 + bb) * TT) * 256 + hq];
        #pragma unroll 4
        for (int t4 = 0; t4 < 124; t4 += 4) {
          f4v b4 = *(const f4v*)&sc[bb][t4];
          acc = fmaf(b4[0], bf2f(xp[(size_t)(t4 + 0) * 256]), acc);
          acc = fmaf(b4[1], bf2f(xp[(size_t)(t4 + 1) * 256]), acc);
          acc = fmaf(b4[2], bf2f(xp[(size_t)(t4 + 2) * 256]), acc);
          acc = fmaf(b4[3], bf2f(xp[(size_t)(t4 + 3) * 256]), acc);
        }
        acc = fmaf(sc[bb][124], bf2f(xp[(size_t)124 * 256]), acc);
        acc = fmaf(sc[bb][125], bf2f(xp[(size_t)125 * 256]), acc);
        acc = fmaf(sc[bb][126], bf2f(xp[(size_t)126 * 256]), acc);
      } else {
        const float* xp = &X[((size_t)(b0 + bb) * TT) * 256 + hq];
        #pragma unroll 4
        for (int t4 = 0; t4 < 124; t4 += 4) {
          f4v b4 = *(const f4v*)&sc[bb][t4];
          acc = fmaf(b4[0], xp[(size_t)(t4 + 0) * 256], acc);
          acc = fmaf(b4[1], xp[(size_t)(t4 + 1) * 256], acc);
          acc = fmaf(b4[2], xp[(size_t)(t4 + 2) * 256], acc);
          acc = fmaf(b4[3], xp[(size_t)(t4 + 3) * 256], acc);
        }
        acc = fmaf(sc[bb][124], xp[(size_t)124 * 256], acc);
        acc = fmaf(sc[bb][125], xp[(size_t)125 * 256], acc);
        acc = fmaf(sc[bb][126], xp[(size_t)126 * 256], acc);
      }
      ctx[bb][hq] = acc;
    }
    __syncthreads();

    // ================= D1: y_tilde (waves 0..3) =================
    if (w < 4) {
      float a = 0.f;
      #pragma unroll
      for (int j = 0; j < 4; ++j) {
        const int m = lane + (j << 6);
        a = fmaf(ctx[w][m], fcw_s[m], a);
      }
      #pragma unroll
      for (int m = 32; m; m >>= 1) a += __shfl_xor(a, m);
      if (lane == 0)
        ytil[w] = a + fcw_s[256] * yprev[(size_t)(b0 + w) * TT + t] + fcb[0];
    }
    __syncthreads();

    // ================= D2/D3: gates + LSTM pointwise =================
    {
      const float yt = ytil[bb];
      const float gi = gts[bb][hq]       + yt * wih_s[hq]       + bsum_s[hq];
      const float gf = gts[bb][hq + 256] + yt * wih_s[hq + 256] + bsum_s[hq + 256];
      const float gg = gts[bb][hq + 512] + yt * wih_s[hq + 512] + bsum_s[hq + 512];
      const float go = gts[bb][hq + 768] + yt * wih_s[hq + 768] + bsum_s[hq + 768];
      creg = sigm(gf) * creg + sigm(gi) * tanh_f(gg);
      dreg = sigm(go) * tanh_f(creg);
      const unsigned short dh = f2bf(dreg);
      const unsigned short dl = f2bf(dreg - bf2f(dh));
      const unsigned short ch = f2bf(creg);
      const unsigned short cl = f2bf(creg - bf2f(ch));
      dcA_hi[bb][hq] = dh;       dcA_lo[bb][hq] = dl;
      dcA_hi[bb][256 + hq] = ch; dcA_lo[bb][256 + hq] = cl;
    }
    __syncthreads();
  }

  // ---- output: y_pred = [d, context]·fcfW^T + fcfb ----
  us_s[bb][hq] = dreg;   // reuse as d buffer
  __syncthreads();
  if (w < 4) {
    float a = 0.f;
    #pragma unroll
    for (int j = 0; j < 4; ++j) {
      const int m = lane + (j << 6);
      a = fmaf(us_s[w][m], fcfw_s[m], a);
      a = fmaf(ctx[w][m], fcfw_s[256 + m], a);
    }
    #pragma unroll
    for (int m = 32; m; m >>= 1) a += __shfl_xor(a, m);
    if (lane == 0) out[b0 + w] = a + fcfb[0];
  }
}

extern "C" void kernel_launch(void* const* d_in, const int* in_sizes, int n_in,
                              void* d_out, int out_size, void* d_ws, size_t ws_size,
                              hipStream_t stream) {
  const float* X    = (const float*)d_in[0];
  const float* yprev= (const float*)d_in[1];
  const float* W1   = (const float*)d_in[2];
  const float* b1   = (const float*)d_in[3];
  const float* W2   = (const float*)d_in[4];
  // d_in[5] = attn_b2: softmax-invariant, unused
  const float* Wih  = (const float*)d_in[6];
  const float* Whh  = (const float*)d_in[7];
  const float* bih  = (const float*)d_in[8];
  const float* bhh  = (const float*)d_in[9];
  const float* fcW  = (const float*)d_in[10];
  const float* fcb  = (const float*)d_in[11];
  const float* fcfW = (const float*)d_in[12];
  const float* fcfb = (const float*)d_in[13];
  float* out = (float*)d_out;

  size_t off = 0;
  char* base = (char*)d_ws;
  auto alloc = [&](size_t bytes) -> void* {
    void* p = base + off;
    off += (bytes + 255) & ~(size_t)255;
    return p;
  };
  const size_t txBytes = (size_t)1024 * TT * 256 * 2;
  unsigned short* Tx    = (unsigned short*)alloc(txBytes);
  unsigned short* WhhP  = (unsigned short*)alloc((size_t)32768 * 8 * 2);
  unsigned short* W1dcP = (unsigned short*)alloc((size_t)16384 * 8 * 2);
  float* W1xT           = (float*)alloc((size_t)256 * 256 * 4);
  unsigned short* Xbf = nullptr;
  if (ws_size >= off + txBytes + 1024) Xbf = (unsigned short*)alloc(txBytes);
  (void)in_sizes; (void)n_in; (void)out_size;

  k_pack_whh<<<128, 256, 0, stream>>>(Whh, WhhP);
  k_pack_w1dc<<<64, 256, 0, stream>>>(W1, W1dcP);
  k_tr_w1x<<<256, 256, 0, stream>>>(W1, W1xT);
  dim3 gg(2032, 4);
  k_gemm_tx<<<gg, 256, 0, stream>>>(X, W1xT, b1, Tx);
  if (Xbf) {
    k_xbf<<<32512, 256, 0, stream>>>(X, Xbf);
    k_main<1><<<256, 1024, 0, stream>>>(X, Tx, Xbf, WhhP, W1dcP, yprev, W2,
                                        Wih, bih, bhh, fcW, fcb, fcfW, fcfb, out);
  } else {
    k_main<0><<<256, 1024, 0, stream>>>(X, Tx, nullptr, WhhP, W1dcP, yprev, W2,
                                        Wih, bih, bhh, fcW, fcb, fcfW, fcfb, out);
  }
}

// Round 3
// 15267.651 us; speedup vs baseline: 1.0319x; 1.0319x over previous
//
#include <hip/hip_runtime.h>
#include <hip/hip_bf16.h>

#define TT 127

typedef __attribute__((ext_vector_type(8))) short s8v;
typedef __attribute__((ext_vector_type(4))) float f4v;
typedef __attribute__((ext_vector_type(4))) unsigned int u4v;

__device__ __forceinline__ float bf2f(unsigned short u){
  union { unsigned int i; float f; } v; v.i = ((unsigned int)u) << 16; return v.f;
}
__device__ __forceinline__ float u2f_lo(unsigned int u){
  union { unsigned int i; float f; } v; v.i = u << 16; return v.f;
}
__device__ __forceinline__ float u2f_hi(unsigned int u){
  union { unsigned int i; float f; } v; v.i = u & 0xffff0000u; return v.f;
}
__device__ __forceinline__ unsigned short f2bf(float f){
  union { float f; unsigned int i; } v; v.f = f;
  unsigned int r = v.i + 0x7FFFu + ((v.i >> 16) & 1u);
  return (unsigned short)(r >> 16);
}
__device__ __forceinline__ float fexp2(float x){ return __builtin_amdgcn_exp2f(x); }
__device__ __forceinline__ float frcp(float x){ return __builtin_amdgcn_rcpf(x); }
__device__ __forceinline__ float sigm(float x){
  return frcp(1.f + fexp2(-1.4426950408889634f * x));
}
__device__ __forceinline__ float tanh_f(float x){
  return 1.f - 2.f * frcp(1.f + fexp2(2.8853900817779268f * x));
}
__device__ __forceinline__ f4v mfma16(s8v a, s8v b, f4v c){
  return __builtin_amdgcn_mfma_f32_16x16x32_bf16(a, b, c, 0, 0, 0);
}

// ---------- prep: pack Whh into per-wave MFMA B-fragments (bf16) ----------
__global__ void k_pack_whh(const float* __restrict__ Whh, unsigned short* __restrict__ WhhP){
  int idx = blockIdx.x * 256 + threadIdx.x;   // 32768
  int lane = idx & 63;
  int f = (idx >> 6) & 31;
  int w = idx >> 11;
  int ct = f >> 3, kt = f & 7;
  int g = (w * 4 + ct) * 16 + (lane & 15);
  int i0 = kt * 32 + (lane >> 4) * 8;
  #pragma unroll
  for (int j = 0; j < 8; ++j)
    WhhP[idx * 8 + j] = f2bf(Whh[g * 256 + i0 + j]);
}

__global__ void k_pack_w1dc(const float* __restrict__ W1, unsigned short* __restrict__ W1dcP){
  int idx = blockIdx.x * 256 + threadIdx.x;   // 16384
  int lane = idx & 63;
  int kt = (idx >> 6) & 15;
  int w = idx >> 10;
  int h = w * 16 + (lane & 15);
  int i0 = kt * 32 + (lane >> 4) * 8;
  #pragma unroll
  for (int j = 0; j < 8; ++j)
    W1dcP[idx * 8 + j] = f2bf(W1[h * 768 + i0 + j]);
}

__global__ void k_tr_w1x(const float* __restrict__ W1, float* __restrict__ W1xT){
  int idx = blockIdx.x * 256 + threadIdx.x;   // 256*256
  int k = idx >> 8, h = idx & 255;
  W1xT[idx] = W1[h * 768 + 512 + k];
}

// ---------- prep: XbfT[b][h][128] = bf16(X[b][t][h]), t padded with 0 ----------
__global__ void k_xbfT(const float* __restrict__ X, unsigned short* __restrict__ XT){
  const int b = blockIdx.x >> 4, grp = blockIdx.x & 15;
  const int hh = threadIdx.x;   // 256
  s8v v;
  #pragma unroll
  for (int j = 0; j < 8; ++j) {
    const int t = grp * 8 + j;
    const float x = (t < TT) ? X[((size_t)b * TT + t) * 256 + hh] : 0.f;
    v[j] = (short)f2bf(x);
  }
  *(s8v*)&XT[(((size_t)b * 256 + hh) << 7) + grp * 8] = v;
}

// ---------- prep: Tx[b,t,h] = tanh( X[b,t,:]·W1x[h,:] + b1[h] ), bf16 ----------
__global__ __launch_bounds__(256) void k_gemm_tx(
    const float* __restrict__ X, const float* __restrict__ W1xT,
    const float* __restrict__ b1, unsigned short* __restrict__ Tx)
{
  __shared__ float As[16][64];
  __shared__ float Bs[16][64];
  const int row0 = blockIdx.x * 64;
  const int col0 = blockIdx.y * 64;
  const int tid = threadIdx.x;
  const int tx = tid & 15, ty = tid >> 4;
  float acc[4][4] = {};
  for (int k0 = 0; k0 < 256; k0 += 16) {
    {
      const int rr = tid & 63, kk4 = (tid >> 6) << 2;
      float4 v = *(const float4*)&X[(size_t)(row0 + rr) * 256 + k0 + kk4];
      As[kk4 + 0][rr] = v.x; As[kk4 + 1][rr] = v.y;
      As[kk4 + 2][rr] = v.z; As[kk4 + 3][rr] = v.w;
    }
    {
      const int cc = tid & 63, kb = tid >> 6;
      #pragma unroll
      for (int j = 0; j < 4; ++j)
        Bs[kb + 4 * j][cc] = W1xT[(size_t)(k0 + kb + 4 * j) * 256 + col0 + cc];
    }
    __syncthreads();
    #pragma unroll
    for (int kk = 0; kk < 16; ++kk) {
      float4 a4 = *(const float4*)&As[kk][ty << 2];
      float4 b4 = *(const float4*)&Bs[kk][tx << 2];
      float av[4] = {a4.x, a4.y, a4.z, a4.w};
      float bv[4] = {b4.x, b4.y, b4.z, b4.w};
      #pragma unroll
      for (int i = 0; i < 4; ++i)
        #pragma unroll
        for (int j = 0; j < 4; ++j)
          acc[i][j] = fmaf(av[i], bv[j], acc[i][j]);
    }
    __syncthreads();
  }
  const int c = col0 + (tx << 2);
  #pragma unroll
  for (int i = 0; i < 4; ++i) {
    const int r = row0 + (ty << 2) + i;
    ushort4 o;
    o.x = f2bf(tanhf(acc[i][0] + b1[c + 0]));
    o.y = f2bf(tanhf(acc[i][1] + b1[c + 1]));
    o.z = f2bf(tanhf(acc[i][2] + b1[c + 2]));
    o.w = f2bf(tanhf(acc[i][3] + b1[c + 3]));
    *(ushort4*)&Tx[(size_t)r * 256 + c] = o;
  }
}

// ---------- main: 256 blocks x 1024 threads, 4 batch/block ----------
template<int USE_XT>
__global__ __launch_bounds__(1024, 4) void k_main(
    const float* __restrict__ X,
    const unsigned short* __restrict__ Tx,
    const unsigned short* __restrict__ XbfT,
    const unsigned short* __restrict__ WhhP,
    const unsigned short* __restrict__ W1dcP,
    const float* __restrict__ yprev,
    const float* __restrict__ W2,
    const float* __restrict__ Wih,
    const float* __restrict__ bih,
    const float* __restrict__ bhh,
    const float* __restrict__ fcW,
    const float* __restrict__ fcb,
    const float* __restrict__ fcfW,
    const float* __restrict__ fcfb,
    float* __restrict__ out)
{
  // dcA rows 0..3 = hi(batch 0..3), rows 4..7 = lo(batch 0..3); cols 0..255=d, 256..511=c
  __shared__ __align__(16) unsigned short dcA[8][520];
  __shared__ __align__(16) float us_s[4][320];   // idx(h) = h + ((h>>4)<<2)
  __shared__ __align__(16) float wtu_s[4][320];
  __shared__ __align__(16) float sc[4][128];
  __shared__ __align__(16) float ctx[4][256];
  __shared__ __align__(16) float gts[4][1024];
  __shared__ float w2s[256];
  __shared__ float fcw_s[257];
  __shared__ float fcfw_s[512];
  __shared__ float wih_s[1024];
  __shared__ float bsum_s[1024];
  __shared__ float ytil[4];

  const int tid = threadIdx.x;
  const int lane = tid & 63;
  const int w = tid >> 6;          // wave 0..15
  const int bb = tid >> 8;         // 0..3
  const int hq = tid & 255;        // 0..255
  const int b0 = blockIdx.x << 2;

  // phase-B static per-lane W2 slice
  float w2r[16];
  {
    const int cc0 = lane & 15;
    #pragma unroll
    for (int e4 = 0; e4 < 4; ++e4) {
      f4v v = *(const f4v*)&W2[cc0 * 16 + e4 * 4];
      w2r[e4*4+0] = v[0]; w2r[e4*4+1] = v[1]; w2r[e4*4+2] = v[2]; w2r[e4*4+3] = v[3];
    }
  }

  if (tid < 256) w2s[tid] = W2[tid];
  if (tid < 257) fcw_s[tid] = fcW[tid];
  if (tid < 512) fcfw_s[tid] = fcfW[tid];
  wih_s[tid] = Wih[tid];
  bsum_s[tid] = bih[tid] + bhh[tid];
  for (int i = tid; i < 8 * 520; i += 1024)
    (&dcA[0][0])[i] = 0;
  float creg = 0.f, dreg = 0.f;
  __syncthreads();

  const int arow = lane & 15;
  const bool arOK = arow < 8;
  const char* dcbase = (const char*)&dcA[0][0] + arow * 1040 + ((lane >> 4) << 4);
  const unsigned short* w1base = &W1dcP[((size_t)w * 16 * 64 + lane) * 8];
  const unsigned short* whbase = &WhhP[((size_t)w * 32 * 64 + lane) * 8];

  for (int t = 0; t < TT; ++t) {
    // ================= A: MFMA  u = [d,c]·W1dc^T ; g = d·Whh^T =================
    {
      // resident d-part A-fragments (kt 0..7), hi rows 0..3, lo rows 4..7
      s8v adc[8];
      #pragma unroll
      for (int kt = 0; kt < 8; ++kt) {
        s8v v = (s8v)0;
        if (arOK) v = *(const s8v*)(dcbase + kt * 64);
        adc[kt] = v;
      }
      // --- u ---
      s8v wa[8], wb[8];
      #pragma unroll
      for (int f = 0; f < 8; ++f) wa[f] = *(const s8v*)(w1base + (size_t)f * 512);
      #pragma unroll
      for (int f = 0; f < 8; ++f) wb[f] = *(const s8v*)(w1base + (size_t)(f + 8) * 512);
      f4v au0 = {0.f,0.f,0.f,0.f}, au1 = {0.f,0.f,0.f,0.f};
      #pragma unroll
      for (int kt = 0; kt < 8; ++kt) {
        if (kt & 1) au1 = mfma16(adc[kt], wa[kt], au1);
        else        au0 = mfma16(adc[kt], wa[kt], au0);
      }
      #pragma unroll
      for (int kt = 0; kt < 8; ++kt) {   // c-part transient A-frags
        s8v v = (s8v)0;
        if (arOK) v = *(const s8v*)(dcbase + (8 + kt) * 64);
        if (kt & 1) au1 = mfma16(v, wb[kt], au1);
        else        au0 = mfma16(v, wb[kt], au0);
      }
      f4v au = au0 + au1;
      #pragma unroll
      for (int r = 0; r < 4; ++r) au[r] += __shfl_xor(au[r], 16);
      if (lane < 16) {
        const int hp = w * 20 + lane;       // padded index
        const float w2v = w2s[w * 16 + lane];
        #pragma unroll
        for (int r = 0; r < 4; ++r) {
          const float tu = tanh_f(au[r]);
          us_s[r][hp] = tu;
          wtu_s[r][hp] = w2v * tu;
        }
      }
      // --- g (4 ct chunks of 8 frags, dbuf pairs) ---
      f4v ag0 = {0.f,0.f,0.f,0.f}, ag1 = ag0, ag2 = ag0, ag3 = ag0;
      #pragma unroll
      for (int f = 0; f < 8; ++f) wa[f] = *(const s8v*)(whbase + (size_t)f * 512);
      #pragma unroll
      for (int f = 0; f < 8; ++f) wb[f] = *(const s8v*)(whbase + (size_t)(8 + f) * 512);
      #pragma unroll
      for (int kt = 0; kt < 8; ++kt) ag0 = mfma16(adc[kt], wa[kt], ag0);
      #pragma unroll
      for (int kt = 0; kt < 8; ++kt) ag1 = mfma16(adc[kt], wb[kt], ag1);
      #pragma unroll
      for (int f = 0; f < 8; ++f) wa[f] = *(const s8v*)(whbase + (size_t)(16 + f) * 512);
      #pragma unroll
      for (int f = 0; f < 8; ++f) wb[f] = *(const s8v*)(whbase + (size_t)(24 + f) * 512);
      #pragma unroll
      for (int kt = 0; kt < 8; ++kt) ag2 = mfma16(adc[kt], wa[kt], ag2);
      #pragma unroll
      for (int kt = 0; kt < 8; ++kt) ag3 = mfma16(adc[kt], wb[kt], ag3);
      #pragma unroll
      for (int r = 0; r < 4; ++r) {
        ag0[r] += __shfl_xor(ag0[r], 16);
        ag1[r] += __shfl_xor(ag1[r], 16);
        ag2[r] += __shfl_xor(ag2[r], 16);
        ag3[r] += __shfl_xor(ag3[r], 16);
      }
      if (lane < 16) {
        #pragma unroll
        for (int r = 0; r < 4; ++r) {
          gts[r][(w * 4 + 0) * 16 + lane] = ag0[r];
          gts[r][(w * 4 + 1) * 16 + lane] = ag1[r];
          gts[r][(w * 4 + 2) * 16 + lane] = ag2[r];
          gts[r][(w * 4 + 3) * 16 + lane] = ag3[r];
        }
      }
    }
    __syncthreads();

    // ================= B: scores via tanh addition formula =================
    {
      const int bq = w >> 2;
      const int cc = lane & 15;
      const int g4 = lane >> 4;
      float tur[16], wtur[16];
      #pragma unroll
      for (int e4 = 0; e4 < 4; ++e4) {
        f4v tv = *(const f4v*)&us_s[bq][cc * 20 + e4 * 4];
        f4v wv = *(const f4v*)&wtu_s[bq][cc * 20 + e4 * 4];
        tur[e4*4+0] = tv[0]; tur[e4*4+1] = tv[1]; tur[e4*4+2] = tv[2]; tur[e4*4+3] = tv[3];
        wtur[e4*4+0] = wv[0]; wtur[e4*4+1] = wv[1]; wtur[e4*4+2] = wv[2]; wtur[e4*4+3] = wv[3];
      }
      const unsigned short* txb = &Tx[((size_t)(b0 + bq) * TT) * 256 + cc * 16];
      #pragma unroll
      for (int it = 0; it < 8; ++it) {
        const int tt = it * 16 + (w & 3) * 4 + g4;
        const int ttc = tt < 126 ? tt : 126;
        const unsigned short* p = txb + (size_t)ttc * 256;
        s8v xa = __builtin_nontemporal_load((const s8v*)p);
        s8v xb = __builtin_nontemporal_load((const s8v*)(p + 8));
        float acc = 0.f;
        #pragma unroll
        for (int e = 0; e < 8; ++e) {
          const float x = bf2f((unsigned short)xa[e]);
          const float den = fmaf(tur[e], x, 1.f);
          const float num = fmaf(w2r[e], x, wtur[e]);
          acc = fmaf(num, frcp(den), acc);
        }
        #pragma unroll
        for (int e = 0; e < 8; ++e) {
          const float x = bf2f((unsigned short)xb[e]);
          const float den = fmaf(tur[8 + e], x, 1.f);
          const float num = fmaf(w2r[8 + e], x, wtur[8 + e]);
          acc = fmaf(num, frcp(den), acc);
        }
        acc += __shfl_xor(acc, 1);
        acc += __shfl_xor(acc, 2);
        acc += __shfl_xor(acc, 4);
        acc += __shfl_xor(acc, 8);
        if (cc == 0 && tt < TT) sc[bq][tt] = acc;
      }
    }
    __syncthreads();

    // ================= softmax (waves 0..3) =================
    if (w < 4) {
      const float s0 = sc[w][lane];
      const float s1 = (lane < 63) ? sc[w][lane + 64] : -3.0e38f;
      float mx = fmaxf(s0, s1);
      #pragma unroll
      for (int m = 32; m; m >>= 1) mx = fmaxf(mx, __shfl_xor(mx, m));
      const float p0 = fexp2((s0 - mx) * 1.4426950408889634f);
      const float p1 = (lane < 63) ? fexp2((s1 - mx) * 1.4426950408889634f) : 0.f;
      float sm = p0 + p1;
      #pragma unroll
      for (int m = 32; m; m >>= 1) sm += __shfl_xor(sm, m);
      const float inv = frcp(sm);
      sc[w][lane] = p0 * inv;
      if (lane < 63) sc[w][lane + 64] = p1 * inv;
      else sc[w][127] = 0.f;
    }
    __syncthreads();

    // ================= C: context =================
    {
      float acc = 0.f;
      if constexpr (USE_XT) {
        const unsigned short* xr = &XbfT[(((size_t)(b0 + bb)) * 256 + hq) << 7];
        #pragma unroll
        for (int g = 0; g < 16; ++g) {
          u4v dv = __builtin_nontemporal_load((const u4v*)(xr + g * 8));
          f4v s0 = *(const f4v*)&sc[bb][g * 8];
          f4v s1 = *(const f4v*)&sc[bb][g * 8 + 4];
          acc = fmaf(s0[0], u2f_lo(dv[0]), acc);
          acc = fmaf(s0[1], u2f_hi(dv[0]), acc);
          acc = fmaf(s0[2], u2f_lo(dv[1]), acc);
          acc = fmaf(s0[3], u2f_hi(dv[1]), acc);
          acc = fmaf(s1[0], u2f_lo(dv[2]), acc);
          acc = fmaf(s1[1], u2f_hi(dv[2]), acc);
          acc = fmaf(s1[2], u2f_lo(dv[3]), acc);
          acc = fmaf(s1[3], u2f_hi(dv[3]), acc);
        }
      } else {
        const float* xp = &X[((size_t)(b0 + bb) * TT) * 256 + hq];
        #pragma unroll 4
        for (int t4 = 0; t4 < 124; t4 += 4) {
          f4v b4 = *(const f4v*)&sc[bb][t4];
          acc = fmaf(b4[0], xp[(size_t)(t4 + 0) * 256], acc);
          acc = fmaf(b4[1], xp[(size_t)(t4 + 1) * 256], acc);
          acc = fmaf(b4[2], xp[(size_t)(t4 + 2) * 256], acc);
          acc = fmaf(b4[3], xp[(size_t)(t4 + 3) * 256], acc);
        }
        acc = fmaf(sc[bb][124], xp[(size_t)124 * 256], acc);
        acc = fmaf(sc[bb][125], xp[(size_t)125 * 256], acc);
        acc = fmaf(sc[bb][126], xp[(size_t)126 * 256], acc);
      }
      ctx[bb][hq] = acc;
    }
    __syncthreads();

    // ================= D1: y_tilde (waves 0..3) =================
    if (w < 4) {
      float a = 0.f;
      #pragma unroll
      for (int j = 0; j < 4; ++j) {
        const int m = lane + (j << 6);
        a = fmaf(ctx[w][m], fcw_s[m], a);
      }
      #pragma unroll
      for (int m = 32; m; m >>= 1) a += __shfl_xor(a, m);
      if (lane == 0)
        ytil[w] = a + fcw_s[256] * yprev[(size_t)(b0 + w) * TT + t] + fcb[0];
    }
    __syncthreads();

    // ================= D2/D3: gates + LSTM pointwise =================
    {
      const float yt = ytil[bb];
      const float gi = gts[bb][hq]       + yt * wih_s[hq]       + bsum_s[hq];
      const float gf = gts[bb][hq + 256] + yt * wih_s[hq + 256] + bsum_s[hq + 256];
      const float gg = gts[bb][hq + 512] + yt * wih_s[hq + 512] + bsum_s[hq + 512];
      const float go = gts[bb][hq + 768] + yt * wih_s[hq + 768] + bsum_s[hq + 768];
      creg = sigm(gf) * creg + sigm(gi) * tanh_f(gg);
      dreg = sigm(go) * tanh_f(creg);
      const unsigned short dh = f2bf(dreg);
      const unsigned short dl = f2bf(dreg - bf2f(dh));
      const unsigned short ch = f2bf(creg);
      const unsigned short cl = f2bf(creg - bf2f(ch));
      dcA[bb][hq] = dh;           dcA[bb + 4][hq] = dl;
      dcA[bb][256 + hq] = ch;     dcA[bb + 4][256 + hq] = cl;
    }
    __syncthreads();
  }

  // ---- output: y_pred = [d, context]·fcfW^T + fcfb ----
  ctx[bb][hq] = ctx[bb][hq];     // ctx holds final context
  us_s[bb][hq] = dreg;           // reuse as final-d buffer (unpadded region ok)
  __syncthreads();
  if (w < 4) {
    float a = 0.f;
    #pragma unroll
    for (int j = 0; j < 4; ++j) {
      const int m = lane + (j << 6);
      a = fmaf(us_s[w][m], fcfw_s[m], a);
      a = fmaf(ctx[w][m], fcfw_s[256 + m], a);
    }
    #pragma unroll
    for (int m = 32; m; m >>= 1) a += __shfl_xor(a, m);
    if (lane == 0) out[b0 + w] = a + fcfb[0];
  }
}

extern "C" void kernel_launch(void* const* d_in, const int* in_sizes, int n_in,
                              void* d_out, int out_size, void* d_ws, size_t ws_size,
                              hipStream_t stream) {
  const float* X    = (const float*)d_in[0];
  const float* yprev= (const float*)d_in[1];
  const float* W1   = (const float*)d_in[2];
  const float* b1   = (const float*)d_in[3];
  const float* W2   = (const float*)d_in[4];
  // d_in[5] = attn_b2: softmax-invariant, unused
  const float* Wih  = (const float*)d_in[6];
  const float* Whh  = (const float*)d_in[7];
  const float* bih  = (const float*)d_in[8];
  const float* bhh  = (const float*)d_in[9];
  const float* fcW  = (const float*)d_in[10];
  const float* fcb  = (const float*)d_in[11];
  const float* fcfW = (const float*)d_in[12];
  const float* fcfb = (const float*)d_in[13];
  float* out = (float*)d_out;

  size_t off = 0;
  char* base = (char*)d_ws;
  auto alloc = [&](size_t bytes) -> void* {
    void* p = base + off;
    off += (bytes + 255) & ~(size_t)255;
    return p;
  };
  const size_t txBytes = (size_t)1024 * TT * 256 * 2;
  const size_t xtBytes = (size_t)1024 * 256 * 128 * 2;
  unsigned short* Tx    = (unsigned short*)alloc(txBytes);
  unsigned short* WhhP  = (unsigned short*)alloc((size_t)32768 * 8 * 2);
  unsigned short* W1dcP = (unsigned short*)alloc((size_t)16384 * 8 * 2);
  float* W1xT           = (float*)alloc((size_t)256 * 256 * 4);
  unsigned short* XbfT = nullptr;
  if (ws_size >= off + xtBytes + 1024) XbfT = (unsigned short*)alloc(xtBytes);
  (void)in_sizes; (void)n_in; (void)out_size;

  k_pack_whh<<<128, 256, 0, stream>>>(Whh, WhhP);
  k_pack_w1dc<<<64, 256, 0, stream>>>(W1, W1dcP);
  k_tr_w1x<<<256, 256, 0, stream>>>(W1, W1xT);
  dim3 gg(2032, 4);
  k_gemm_tx<<<gg, 256, 0, stream>>>(X, W1xT, b1, Tx);
  if (XbfT) {
    k_xbfT<<<16384, 256, 0, stream>>>(X, XbfT);
    k_main<1><<<256, 1024, 0, stream>>>(X, Tx, XbfT, WhhP, W1dcP, yprev, W2,
                                        Wih, bih, bhh, fcW, fcb, fcfW, fcfb, out);
  } else {
    k_main<0><<<256, 1024, 0, stream>>>(X, Tx, nullptr, WhhP, W1dcP, yprev, W2,
                                        Wih, bih, bhh, fcW, fcb, fcfW, fcfb, out);
  }
}

// Round 7
// 6959.564 us; speedup vs baseline: 2.2638x; 2.1938x over previous
//
#include <hip/hip_runtime.h>
#include <hip/hip_bf16.h>

#define TT 127

typedef __attribute__((ext_vector_type(8))) short s8v;
typedef __attribute__((ext_vector_type(4))) float f4v;
typedef __attribute__((ext_vector_type(4))) unsigned int u4v;

__device__ __forceinline__ float bf2f(unsigned short u){
  union { unsigned int i; float f; } v; v.i = ((unsigned int)u) << 16; return v.f;
}
__device__ __forceinline__ float u2f_lo(unsigned int u){
  union { unsigned int i; float f; } v; v.i = u << 16; return v.f;
}
__device__ __forceinline__ float u2f_hi(unsigned int u){
  union { unsigned int i; float f; } v; v.i = u & 0xffff0000u; return v.f;
}
__device__ __forceinline__ unsigned short f2bf(float f){
  union { float f; unsigned int i; } v; v.f = f;
  unsigned int r = v.i + 0x7FFFu + ((v.i >> 16) & 1u);
  return (unsigned short)(r >> 16);
}
__device__ __forceinline__ float fexp2(float x){ return __builtin_amdgcn_exp2f(x); }
__device__ __forceinline__ float frcp(float x){ return __builtin_amdgcn_rcpf(x); }
__device__ __forceinline__ float sigm(float x){
  return frcp(1.f + fexp2(-1.4426950408889634f * x));
}
__device__ __forceinline__ float tanh_f(float x){
  return 1.f - 2.f * frcp(1.f + fexp2(2.8853900817779268f * x));
}
__device__ __forceinline__ f4v mfma16(s8v a, s8v b, f4v c){
  return __builtin_amdgcn_mfma_f32_16x16x32_bf16(a, b, c, 0, 0, 0);
}
__device__ __forceinline__ void barrier_lgkm(){
  asm volatile("s_waitcnt lgkmcnt(0)" ::: "memory");
  __builtin_amdgcn_s_barrier();
}

// ---------- prep: pack weights chunk-major for the LDS ring ----------
// WP chunk F (16KB = [wave 0..15][lane 0..63][16B]): F=0..15 -> W1dc kt=F; F=16..47 -> Whh f=F-16 (f=ct*8+kt)
__global__ void k_pack_w1dc(const float* __restrict__ W1, unsigned short* __restrict__ WP){
  int n = blockIdx.x * 256 + threadIdx.x;   // 16384 = [kt][w][lane]
  int lane = n & 63, w = (n >> 6) & 15, kt = n >> 10;
  int h = w * 16 + (lane & 15);
  int i0 = kt * 32 + (lane >> 4) * 8;
  #pragma unroll
  for (int j = 0; j < 8; ++j)
    WP[(size_t)n * 8 + j] = f2bf(W1[h * 768 + i0 + j]);
}
__global__ void k_pack_whh(const float* __restrict__ Whh, unsigned short* __restrict__ WP){
  int n = blockIdx.x * 256 + threadIdx.x;   // 32768 = [f][w][lane]
  int lane = n & 63, w = (n >> 6) & 15, f = n >> 10;
  int ct = f >> 3, kt = f & 7;
  int g = (w * 4 + ct) * 16 + (lane & 15);
  int i0 = kt * 32 + (lane >> 4) * 8;
  #pragma unroll
  for (int j = 0; j < 8; ++j)
    WP[131072 + (size_t)n * 8 + j] = f2bf(Whh[g * 256 + i0 + j]);
}

__global__ void k_tr_w1x(const float* __restrict__ W1, float* __restrict__ W1xT){
  int idx = blockIdx.x * 256 + threadIdx.x;   // 256*256
  int k = idx >> 8, h = idx & 255;
  W1xT[idx] = W1[h * 768 + 512 + k];
}

// ---------- prep: XT2[b][g][h][8] = bf16(X[b][g*8+j][h]) (t padded to 128 with 0) ----------
__global__ void k_xbfT(const float* __restrict__ X, unsigned short* __restrict__ XT){
  const int b = blockIdx.x >> 4, g = blockIdx.x & 15;
  const int h = threadIdx.x;
  s8v v;
  #pragma unroll
  for (int j = 0; j < 8; ++j) {
    const int t = g * 8 + j;
    float x = 0.f;
    if (t < TT) x = X[((size_t)b * TT + t) * 256 + h];
    v[j] = (short)f2bf(x);
  }
  *(s8v*)&XT[((size_t)(b * 16 + g) * 256 + h) * 8] = v;
}

// ---------- prep: Tx[b,t,h] = tanh( X[b,t,:]·W1x[h,:] + b1[h] ), bf16 ----------
__global__ __launch_bounds__(256) void k_gemm_tx(
    const float* __restrict__ X, const float* __restrict__ W1xT,
    const float* __restrict__ b1, unsigned short* __restrict__ Tx)
{
  __shared__ float As[16][64];
  __shared__ float Bs[16][64];
  const int row0 = blockIdx.x * 64;
  const int col0 = blockIdx.y * 64;
  const int tid = threadIdx.x;
  const int tx = tid & 15, ty = tid >> 4;
  float acc[4][4] = {};
  for (int k0 = 0; k0 < 256; k0 += 16) {
    {
      const int rr = tid & 63, kk4 = (tid >> 6) << 2;
      float4 v = *(const float4*)&X[(size_t)(row0 + rr) * 256 + k0 + kk4];
      As[kk4 + 0][rr] = v.x; As[kk4 + 1][rr] = v.y;
      As[kk4 + 2][rr] = v.z; As[kk4 + 3][rr] = v.w;
    }
    {
      const int cc = tid & 63, kb = tid >> 6;
      #pragma unroll
      for (int j = 0; j < 4; ++j)
        Bs[kb + 4 * j][cc] = W1xT[(size_t)(k0 + kb + 4 * j) * 256 + col0 + cc];
    }
    __syncthreads();
    #pragma unroll
    for (int kk = 0; kk < 16; ++kk) {
      float4 a4 = *(const float4*)&As[kk][ty << 2];
      float4 b4 = *(const float4*)&Bs[kk][tx << 2];
      float av[4] = {a4.x, a4.y, a4.z, a4.w};
      float bv[4] = {b4.x, b4.y, b4.z, b4.w};
      #pragma unroll
      for (int i = 0; i < 4; ++i)
        #pragma unroll
        for (int j = 0; j < 4; ++j)
          acc[i][j] = fmaf(av[i], bv[j], acc[i][j]);
    }
    __syncthreads();
  }
  const int c = col0 + (tx << 2);
  #pragma unroll
  for (int i = 0; i < 4; ++i) {
    const int r = row0 + (ty << 2) + i;
    ushort4 o;
    o.x = f2bf(tanhf(acc[i][0] + b1[c + 0]));
    o.y = f2bf(tanhf(acc[i][1] + b1[c + 1]));
    o.z = f2bf(tanhf(acc[i][2] + b1[c + 2]));
    o.w = f2bf(tanhf(acc[i][3] + b1[c + 3]));
    *(ushort4*)&Tx[(size_t)r * 256 + c] = o;
  }
}

// ---------- main: 256 blocks x 1024 threads, 4 batch/block, LDS weight ring ----------
template<int USE_XT>
__global__ __launch_bounds__(1024, 4) void k_main(
    const float* __restrict__ X,
    const unsigned short* __restrict__ Tx,
    const unsigned short* __restrict__ XT2,
    const unsigned short* __restrict__ WP,
    const float* __restrict__ yprev,
    const float* __restrict__ W2,
    const float* __restrict__ Wih,
    const float* __restrict__ bih,
    const float* __restrict__ bhh,
    const float* __restrict__ fcW,
    const float* __restrict__ fcb,
    const float* __restrict__ fcfW,
    const float* __restrict__ fcfb,
    float* __restrict__ out)
{
  __shared__ __align__(16) char wring[6 * 16384];            // 96KB weight ring
  __shared__ __align__(16) unsigned short dcA[8][520];       // rows 0-3 hi(b0..3), 4-7 lo; cols 0-255 d, 256-511 c
  __shared__ __align__(16) float us_s[4][320];               // padded: idx = w*20 + lane
  __shared__ __align__(16) float sc[4][128];
  __shared__ __align__(16) float ctx[4][256];
  __shared__ __align__(16) float gts[4][1024];
  __shared__ float w2s[256];
  __shared__ float fcw_s[257];
  __shared__ float fcfw_s[512];
  __shared__ float wih_s[1024];
  __shared__ float bsum_s[1024];
  __shared__ float yp_s[4][128];
  __shared__ float ytil[4];

  const int tid = threadIdx.x;
  const int lane = tid & 63;
  const int w = tid >> 6;          // wave 0..15
  const int bb = tid >> 8;         // 0..3
  const int hq = tid & 255;        // 0..255
  const int b0 = blockIdx.x << 2;

  if (tid < 256) w2s[tid] = W2[tid];
  if (tid < 257) fcw_s[tid] = fcW[tid];
  if (tid < 512) fcfw_s[tid] = fcfW[tid];
  wih_s[tid] = Wih[tid];
  bsum_s[tid] = bih[tid] + bhh[tid];
  if (tid < 512 && (tid & 127) < TT)
    yp_s[tid >> 7][tid & 127] = yprev[(size_t)(b0 + (tid >> 7)) * TT + (tid & 127)];
  for (int i = tid; i < 8 * 520; i += 1024)
    (&dcA[0][0])[i] = 0;
  const float fcb0 = fcb[0];
  const float fcfb0 = fcfb[0];
  float creg = 0.f, dreg = 0.f;
  barrier_lgkm();

  const int arow = lane & 15;
  const bool arOK = arow < 8;
  const char* dcbase = (const char*)&dcA[0][0] + arow * 1040 + ((lane >> 4) << 4);
  const int wlo = w * 1024 + lane * 16;                      // per-lane byte offset inside a chunk
  const char* WPc = (const char*)WP;
  const char* wslice = wring + wlo;                          // per-lane LDS read base
  char* wdst = wring + w * 1024;                             // wave-uniform LDS DMA dst base

  // prologue: stage chunks 0..5 into ring slots 0..5
  #pragma unroll
  for (int F = 0; F < 6; ++F) {
    __builtin_amdgcn_global_load_lds((const unsigned int*)(WPc + (size_t)F * 16384 + wlo),
                                     (unsigned int*)(wdst + F * 16384), 16, 0, 0);
  }
  asm volatile("s_waitcnt vmcnt(5)" ::: "memory");
  __builtin_amdgcn_sched_barrier(0);
  s8v bnext = *(const s8v*)(wslice);                         // chunk 0 fragment

  for (int t = 0; t < TT; ++t) {
    // ================= A: MFMA  u = [d,c]·W1dc^T ; g = d·Whh^T (ring-fed, period-48) =================
    {
      s8v adc[8];
      #pragma unroll
      for (int kt = 0; kt < 8; ++kt) {
        s8v v = (s8v)0;
        if (arOK) v = *(const s8v*)(dcbase + kt * 64);
        adc[kt] = v;
      }
      f4v au0 = {0.f,0.f,0.f,0.f}, au1 = au0;
      f4v ag[4]; ag[0] = au0; ag[1] = au0; ag[2] = au0; ag[3] = au0;
      #pragma unroll
      for (int f = 0; f < 48; ++f) {
        s8v bcur = bnext;
        asm volatile("s_waitcnt vmcnt(4)" ::: "memory");
        __builtin_amdgcn_sched_barrier(0);
        bnext = *(const s8v*)(wslice + (((f + 1) % 6) * 16384));
        if (f < 8) {
          if (f & 1) au1 = mfma16(adc[f], bcur, au1);
          else       au0 = mfma16(adc[f], bcur, au0);
        } else if (f < 16) {
          s8v cv = (s8v)0;
          if (arOK) cv = *(const s8v*)(dcbase + f * 64);
          if (f & 1) au1 = mfma16(cv, bcur, au1);
          else       au0 = mfma16(cv, bcur, au0);
        } else {
          ag[(f - 16) >> 3] = mfma16(adc[f & 7], bcur, ag[(f - 16) >> 3]);
        }
        // periodic prefetch: chunk (f+6) mod 48 into slot f%6 (same sequence every step)
        const int nf = (f + 6) % 48;
        __builtin_amdgcn_global_load_lds((const unsigned int*)(WPc + (size_t)nf * 16384 + wlo),
                                         (unsigned int*)(wdst + (f % 6) * 16384), 16, 0, 0);
      }
      f4v au = au0 + au1;
      #pragma unroll
      for (int r = 0; r < 4; ++r) au[r] += __shfl_xor(au[r], 16);
      #pragma unroll
      for (int r = 0; r < 4; ++r) {
        ag[r][0] += __shfl_xor(ag[r][0], 16);
        ag[r][1] += __shfl_xor(ag[r][1], 16);
        ag[r][2] += __shfl_xor(ag[r][2], 16);
        ag[r][3] += __shfl_xor(ag[r][3], 16);
      }
      if (lane < 16) {
        const int hp = w * 20 + lane;
        #pragma unroll
        for (int r = 0; r < 4; ++r)
          us_s[r][hp] = tanh_f(au[r]);
        #pragma unroll
        for (int ct = 0; ct < 4; ++ct) {
          const int g0 = (w * 4 + ct) * 16 + lane;
          #pragma unroll
          for (int r = 0; r < 4; ++r)
            gts[r][g0] = ag[ct][r];
        }
      }
    }
    barrier_lgkm();

    // ================= B: scores via tanh addition formula =================
    {
      const int bq = w >> 2;
      const int cc = lane & 15;
      const int g4 = lane >> 4;
      float tur[16], wr[16], wtur[16];
      #pragma unroll
      for (int e4 = 0; e4 < 4; ++e4) {
        f4v tv = *(const f4v*)&us_s[bq][cc * 20 + e4 * 4];
        f4v wv = *(const f4v*)&w2s[cc * 16 + e4 * 4];
        #pragma unroll
        for (int j = 0; j < 4; ++j) {
          tur[e4 * 4 + j] = tv[j];
          wr[e4 * 4 + j] = wv[j];
          wtur[e4 * 4 + j] = wv[j] * tv[j];
        }
      }
      const unsigned short* txb = &Tx[((size_t)(b0 + bq) * TT) * 256 + cc * 16];
      #pragma unroll
      for (int it = 0; it < 8; ++it) {
        const int tt = it * 16 + (w & 3) * 4 + g4;
        const int ttc = tt < 126 ? tt : 126;
        const unsigned short* p = txb + (size_t)ttc * 256;
        s8v xa = *(const s8v*)p;
        s8v xb = *(const s8v*)(p + 8);
        float acc = 0.f;
        #pragma unroll
        for (int e = 0; e < 8; ++e) {
          const float x = bf2f((unsigned short)xa[e]);
          const float den = fmaf(tur[e], x, 1.f);
          const float num = fmaf(wr[e], x, wtur[e]);
          acc = fmaf(num, frcp(den), acc);
        }
        #pragma unroll
        for (int e = 0; e < 8; ++e) {
          const float x = bf2f((unsigned short)xb[e]);
          const float den = fmaf(tur[8 + e], x, 1.f);
          const float num = fmaf(wr[8 + e], x, wtur[8 + e]);
          acc = fmaf(num, frcp(den), acc);
        }
        acc += __shfl_xor(acc, 1);
        acc += __shfl_xor(acc, 2);
        acc += __shfl_xor(acc, 4);
        acc += __shfl_xor(acc, 8);
        if (cc == 0 && tt < TT) sc[bq][tt] = acc;
      }
    }
    barrier_lgkm();

    // ================= softmax (waves 0..3) =================
    if (w < 4) {
      const float s0 = sc[w][lane];
      const float s1 = (lane < 63) ? sc[w][lane + 64] : -3.0e38f;
      float mx = fmaxf(s0, s1);
      #pragma unroll
      for (int m = 32; m; m >>= 1) mx = fmaxf(mx, __shfl_xor(mx, m));
      const float p0 = fexp2((s0 - mx) * 1.4426950408889634f);
      const float p1 = (lane < 63) ? fexp2((s1 - mx) * 1.4426950408889634f) : 0.f;
      float sm = p0 + p1;
      #pragma unroll
      for (int m = 32; m; m >>= 1) sm += __shfl_xor(sm, m);
      const float inv = frcp(sm);
      sc[w][lane] = p0 * inv;
      if (lane < 63) sc[w][lane + 64] = p1 * inv;
      else sc[w][127] = 0.f;
    }
    barrier_lgkm();

    // ================= C: context =================
    {
      float acc = 0.f;
      if constexpr (USE_XT) {
        const unsigned short* xr = &XT2[((size_t)(b0 + bb) * 16 * 256 + hq) * 8];
        #pragma unroll
        for (int g = 0; g < 16; ++g) {
          u4v dv = *(const u4v*)(xr + (size_t)g * 2048);
          f4v s0 = *(const f4v*)&sc[bb][g * 8];
          f4v s1 = *(const f4v*)&sc[bb][g * 8 + 4];
          acc = fmaf(s0[0], u2f_lo(dv[0]), acc);
          acc = fmaf(s0[1], u2f_hi(dv[0]), acc);
          acc = fmaf(s0[2], u2f_lo(dv[1]), acc);
          acc = fmaf(s0[3], u2f_hi(dv[1]), acc);
          acc = fmaf(s1[0], u2f_lo(dv[2]), acc);
          acc = fmaf(s1[1], u2f_hi(dv[2]), acc);
          acc = fmaf(s1[2], u2f_lo(dv[3]), acc);
          acc = fmaf(s1[3], u2f_hi(dv[3]), acc);
        }
      } else {
        const float* xp = &X[((size_t)(b0 + bb) * TT) * 256 + hq];
        #pragma unroll 4
        for (int t4 = 0; t4 < 124; t4 += 4) {
          f4v b4 = *(const f4v*)&sc[bb][t4];
          acc = fmaf(b4[0], xp[(size_t)(t4 + 0) * 256], acc);
          acc = fmaf(b4[1], xp[(size_t)(t4 + 1) * 256], acc);
          acc = fmaf(b4[2], xp[(size_t)(t4 + 2) * 256], acc);
          acc = fmaf(b4[3], xp[(size_t)(t4 + 3) * 256], acc);
        }
        acc = fmaf(sc[bb][124], xp[(size_t)124 * 256], acc);
        acc = fmaf(sc[bb][125], xp[(size_t)125 * 256], acc);
        acc = fmaf(sc[bb][126], xp[(size_t)126 * 256], acc);
      }
      ctx[bb][hq] = acc;
    }
    barrier_lgkm();

    // ================= D1: y_tilde (waves 0..3) =================
    if (w < 4) {
      float a = 0.f;
      #pragma unroll
      for (int j = 0; j < 4; ++j) {
        const int m = lane + (j << 6);
        a = fmaf(ctx[w][m], fcw_s[m], a);
      }
      #pragma unroll
      for (int m = 32; m; m >>= 1) a += __shfl_xor(a, m);
      if (lane == 0)
        ytil[w] = a + fcw_s[256] * yp_s[w][t] + fcb0;
    }
    barrier_lgkm();

    // ================= D2/D3: gates + LSTM pointwise =================
    {
      const float yt = ytil[bb];
      const float gi = gts[bb][hq]       + yt * wih_s[hq]       + bsum_s[hq];
      const float gf = gts[bb][hq + 256] + yt * wih_s[hq + 256] + bsum_s[hq + 256];
      const float gg = gts[bb][hq + 512] + yt * wih_s[hq + 512] + bsum_s[hq + 512];
      const float go = gts[bb][hq + 768] + yt * wih_s[hq + 768] + bsum_s[hq + 768];
      creg = sigm(gf) * creg + sigm(gi) * tanh_f(gg);
      dreg = sigm(go) * tanh_f(creg);
      const unsigned short dh = f2bf(dreg);
      const unsigned short dl = f2bf(dreg - bf2f(dh));
      const unsigned short ch = f2bf(creg);
      const unsigned short cl = f2bf(creg - bf2f(ch));
      dcA[bb][hq] = dh;           dcA[bb + 4][hq] = dl;
      dcA[bb][256 + hq] = ch;     dcA[bb + 4][256 + hq] = cl;
    }
    barrier_lgkm();
  }

  // ---- output: y_pred = [d, context]·fcfW^T + fcfb ----
  us_s[bb][hq] = dreg;   // reuse (flat) as final-d buffer
  barrier_lgkm();
  if (w < 4) {
    float a = 0.f;
    #pragma unroll
    for (int j = 0; j < 4; ++j) {
      const int m = lane + (j << 6);
      a = fmaf(us_s[w][m], fcfw_s[m], a);
      a = fmaf(ctx[w][m], fcfw_s[256 + m], a);
    }
    #pragma unroll
    for (int m = 32; m; m >>= 1) a += __shfl_xor(a, m);
    if (lane == 0) out[b0 + w] = a + fcfb0;
  }
  asm volatile("s_waitcnt vmcnt(0)" ::: "memory");
}

extern "C" void kernel_launch(void* const* d_in, const int* in_sizes, int n_in,
                              void* d_out, int out_size, void* d_ws, size_t ws_size,
                              hipStream_t stream) {
  const float* X    = (const float*)d_in[0];
  const float* yprev= (const float*)d_in[1];
  const float* W1   = (const float*)d_in[2];
  const float* b1   = (const float*)d_in[3];
  const float* W2   = (const float*)d_in[4];
  // d_in[5] = attn_b2: softmax-invariant, unused
  const float* Wih  = (const float*)d_in[6];
  const float* Whh  = (const float*)d_in[7];
  const float* bih  = (const float*)d_in[8];
  const float* bhh  = (const float*)d_in[9];
  const float* fcW  = (const float*)d_in[10];
  const float* fcb  = (const float*)d_in[11];
  const float* fcfW = (const float*)d_in[12];
  const float* fcfb = (const float*)d_in[13];
  float* out = (float*)d_out;

  size_t off = 0;
  char* base = (char*)d_ws;
  auto alloc = [&](size_t bytes) -> void* {
    void* p = base + off;
    off += (bytes + 255) & ~(size_t)255;
    return p;
  };
  const size_t txBytes = (size_t)1024 * TT * 256 * 2;
  const size_t xtBytes = (size_t)1024 * 16 * 256 * 8 * 2;
  unsigned short* Tx   = (unsigned short*)alloc(txBytes);
  unsigned short* WP   = (unsigned short*)alloc((size_t)48 * 16384);
  float* W1xT          = (float*)alloc((size_t)256 * 256 * 4);
  unsigned short* XT2 = nullptr;
  if (ws_size >= off + xtBytes + 1024) XT2 = (unsigned short*)alloc(xtBytes);
  (void)in_sizes; (void)n_in; (void)out_size;

  k_pack_w1dc<<<64, 256, 0, stream>>>(W1, WP);
  k_pack_whh<<<128, 256, 0, stream>>>(Whh, WP);
  k_tr_w1x<<<256, 256, 0, stream>>>(W1, W1xT);
  dim3 gg(2032, 4);
  k_gemm_tx<<<gg, 256, 0, stream>>>(X, W1xT, b1, Tx);
  if (XT2) {
    k_xbfT<<<16384, 256, 0, stream>>>(X, XT2);
    k_main<1><<<256, 1024, 0, stream>>>(X, Tx, XT2, WP, yprev, W2,
                                        Wih, bih, bhh, fcW, fcb, fcfW, fcfb, out);
  } else {
    k_main<0><<<256, 1024, 0, stream>>>(X, Tx, nullptr, WP, yprev, W2,
                                        Wih, bih, bhh, fcW, fcb, fcfW, fcfb, out);
  }
}

// Round 8
// 6551.727 us; speedup vs baseline: 2.4047x; 1.0622x over previous
//
#include <hip/hip_runtime.h>
#include <hip/hip_bf16.h>

#define TT 127
#define L2E 1.4426950408889634f

typedef __attribute__((ext_vector_type(8))) short s8v;
typedef __attribute__((ext_vector_type(4))) float f4v;
typedef __attribute__((ext_vector_type(4))) unsigned int u4v;

__device__ __forceinline__ float bf2f(unsigned short u){
  union { unsigned int i; float f; } v; v.i = ((unsigned int)u) << 16; return v.f;
}
__device__ __forceinline__ float u2f_lo(unsigned int u){
  union { unsigned int i; float f; } v; v.i = u << 16; return v.f;
}
__device__ __forceinline__ float u2f_hi(unsigned int u){
  union { unsigned int i; float f; } v; v.i = u & 0xffff0000u; return v.f;
}
__device__ __forceinline__ unsigned short f2bf(float f){
  union { float f; unsigned int i; } v; v.f = f;
  unsigned int r = v.i + 0x7FFFu + ((v.i >> 16) & 1u);
  return (unsigned short)(r >> 16);
}
__device__ __forceinline__ float fexp2(float x){ return __builtin_amdgcn_exp2f(x); }
__device__ __forceinline__ float frcp(float x){ return __builtin_amdgcn_rcpf(x); }
__device__ __forceinline__ float sigm(float x){
  return frcp(1.f + fexp2(-L2E * x));
}
__device__ __forceinline__ float tanh_f(float x){
  return 1.f - 2.f * frcp(1.f + fexp2(2.f * L2E * x));
}
__device__ __forceinline__ f4v mfma16(s8v a, s8v b, f4v c){
  return __builtin_amdgcn_mfma_f32_16x16x32_bf16(a, b, c, 0, 0, 0);
}
__device__ __forceinline__ void barrier_lgkm(){
  asm volatile("s_waitcnt lgkmcnt(0)" ::: "memory");
  __builtin_amdgcn_s_barrier();
}

// ---------- prep: pack weights chunk-major for the LDS ring ----------
__global__ void k_pack_w1dc(const float* __restrict__ W1, unsigned short* __restrict__ WP){
  int n = blockIdx.x * 256 + threadIdx.x;   // 16384 = [kt][w][lane]
  int lane = n & 63, w = (n >> 6) & 15, kt = n >> 10;
  int h = w * 16 + (lane & 15);
  int i0 = kt * 32 + (lane >> 4) * 8;
  #pragma unroll
  for (int j = 0; j < 8; ++j)
    WP[(size_t)n * 8 + j] = f2bf(W1[h * 768 + i0 + j]);
}
__global__ void k_pack_whh(const float* __restrict__ Whh, unsigned short* __restrict__ WP){
  int n = blockIdx.x * 256 + threadIdx.x;   // 32768 = [f][w][lane]
  int lane = n & 63, w = (n >> 6) & 15, f = n >> 10;
  int ct = f >> 3, kt = f & 7;
  int g = (w * 4 + ct) * 16 + (lane & 15);
  int i0 = kt * 32 + (lane >> 4) * 8;
  #pragma unroll
  for (int j = 0; j < 8; ++j)
    WP[131072 + (size_t)n * 8 + j] = f2bf(Whh[g * 256 + i0 + j]);
}

__global__ void k_tr_w1x(const float* __restrict__ W1, float* __restrict__ W1xT){
  int idx = blockIdx.x * 256 + threadIdx.x;   // 256*256
  int k = idx >> 8, h = idx & 255;
  W1xT[idx] = W1[h * 768 + 512 + k];
}

// ---------- prep: Xbf[b][t][m] = bf16(X) ----------
__global__ void k_xbf(const float* __restrict__ X, unsigned short* __restrict__ Xbf){
  int idx = blockIdx.x * 256 + threadIdx.x;   // 8323072 quads
  float4 v = ((const float4*)X)[idx];
  ushort4 o;
  o.x = f2bf(v.x); o.y = f2bf(v.y); o.z = f2bf(v.z); o.w = f2bf(v.w);
  ((ushort4*)Xbf)[idx] = o;
}

// ---------- prep: Tx[b,t,h] = tanh( X[b,t,:]·W1x[h,:] + b1[h] ), bf16 ----------
__global__ __launch_bounds__(256) void k_gemm_tx(
    const float* __restrict__ X, const float* __restrict__ W1xT,
    const float* __restrict__ b1, unsigned short* __restrict__ Tx)
{
  __shared__ float As[16][64];
  __shared__ float Bs[16][64];
  const int row0 = blockIdx.x * 64;
  const int col0 = blockIdx.y * 64;
  const int tid = threadIdx.x;
  const int tx = tid & 15, ty = tid >> 4;
  float acc[4][4] = {};
  for (int k0 = 0; k0 < 256; k0 += 16) {
    {
      const int rr = tid & 63, kk4 = (tid >> 6) << 2;
      float4 v = *(const float4*)&X[(size_t)(row0 + rr) * 256 + k0 + kk4];
      As[kk4 + 0][rr] = v.x; As[kk4 + 1][rr] = v.y;
      As[kk4 + 2][rr] = v.z; As[kk4 + 3][rr] = v.w;
    }
    {
      const int cc = tid & 63, kb = tid >> 6;
      #pragma unroll
      for (int j = 0; j < 4; ++j)
        Bs[kb + 4 * j][cc] = W1xT[(size_t)(k0 + kb + 4 * j) * 256 + col0 + cc];
    }
    __syncthreads();
    #pragma unroll
    for (int kk = 0; kk < 16; ++kk) {
      float4 a4 = *(const float4*)&As[kk][ty << 2];
      float4 b4 = *(const float4*)&Bs[kk][tx << 2];
      float av[4] = {a4.x, a4.y, a4.z, a4.w};
      float bv[4] = {b4.x, b4.y, b4.z, b4.w};
      #pragma unroll
      for (int i = 0; i < 4; ++i)
        #pragma unroll
        for (int j = 0; j < 4; ++j)
          acc[i][j] = fmaf(av[i], bv[j], acc[i][j]);
    }
    __syncthreads();
  }
  const int c = col0 + (tx << 2);
  #pragma unroll
  for (int i = 0; i < 4; ++i) {
    const int r = row0 + (ty << 2) + i;
    ushort4 o;
    o.x = f2bf(tanhf(acc[i][0] + b1[c + 0]));
    o.y = f2bf(tanhf(acc[i][1] + b1[c + 1]));
    o.z = f2bf(tanhf(acc[i][2] + b1[c + 2]));
    o.w = f2bf(tanhf(acc[i][3] + b1[c + 3]));
    *(ushort4*)&Tx[(size_t)r * 256 + c] = o;
  }
}

// ---------- main: 256 blocks x 1024 threads, 4 batch/block, LDS weight ring ----------
template<int USE_XB>
__global__ __launch_bounds__(1024, 4) void k_main(
    const float* __restrict__ X,
    const unsigned short* __restrict__ Tx,
    const unsigned short* __restrict__ Xbf,
    const unsigned short* __restrict__ WP,
    const float* __restrict__ yprev,
    const float* __restrict__ W2,
    const float* __restrict__ Wih,
    const float* __restrict__ bih,
    const float* __restrict__ bhh,
    const float* __restrict__ fcW,
    const float* __restrict__ fcb,
    const float* __restrict__ fcfW,
    const float* __restrict__ fcfb,
    float* __restrict__ out)
{
  __shared__ __align__(16) char wring[6 * 16384];            // 96KB weight ring
  __shared__ __align__(16) unsigned short dcA[8][520];
  __shared__ __align__(16) float us_s[4][320];               // padded: idx = w*20 + lane
  __shared__ __align__(16) float MZ_s[4][8];                 // per batch: M_w[0..3], Z_w[4..7]
  __shared__ __align__(16) unsigned short ctxp_s[16][256];   // bf16 ctx partials per wave
  __shared__ __align__(16) float ctx[4][256];
  __shared__ __align__(16) float gts[4][1024];
  __shared__ float w2s[256];
  __shared__ float fcw_s[257];
  __shared__ float fcfw_s[512];
  __shared__ float wih_s[1024];
  __shared__ float bsum_s[1024];
  __shared__ float yp_s[4][128];
  __shared__ float ytil[4];

  const int tid = threadIdx.x;
  const int lane = tid & 63;
  const int w = tid >> 6;          // wave 0..15
  const int bb = tid >> 8;         // 0..3
  const int hq = tid & 255;        // 0..255
  const int b0 = blockIdx.x << 2;

  if (tid < 256) w2s[tid] = W2[tid];
  if (tid < 257) fcw_s[tid] = fcW[tid];
  if (tid < 512) fcfw_s[tid] = fcfW[tid];
  wih_s[tid] = Wih[tid];
  bsum_s[tid] = bih[tid] + bhh[tid];
  if (tid < 512 && (tid & 127) < TT)
    yp_s[tid >> 7][tid & 127] = yprev[(size_t)(b0 + (tid >> 7)) * TT + (tid & 127)];
  for (int i = tid; i < 8 * 520; i += 1024)
    (&dcA[0][0])[i] = 0;
  const float fcb0 = fcb[0];
  const float fcfb0 = fcfb[0];
  float creg = 0.f, dreg = 0.f;
  barrier_lgkm();

  const int arow = lane & 15;
  const bool arOK = arow < 8;
  const char* dcbase = (const char*)&dcA[0][0] + arow * 1040 + ((lane >> 4) << 4);
  const int wlo = w * 1024 + lane * 16;
  const char* WPc = (const char*)WP;
  const char* wslice = wring + wlo;
  char* wdst = wring + w * 1024;

  // prologue: stage chunks 0..5 into ring slots 0..5
  #pragma unroll
  for (int F = 0; F < 6; ++F) {
    __builtin_amdgcn_global_load_lds((const unsigned int*)(WPc + (size_t)F * 16384 + wlo),
                                     (unsigned int*)(wdst + F * 16384), 16, 0, 0);
  }
  asm volatile("s_waitcnt vmcnt(5)" ::: "memory");
  __builtin_amdgcn_sched_barrier(0);
  s8v bnext = *(const s8v*)(wslice);

  for (int t = 0; t < TT; ++t) {
    // ================= A: MFMA  u = [d,c]·W1dc^T ; g = d·Whh^T (ring-fed, period-48) =================
    {
      s8v adc[8];
      #pragma unroll
      for (int kt = 0; kt < 8; ++kt) {
        s8v v = (s8v)0;
        if (arOK) v = *(const s8v*)(dcbase + kt * 64);
        adc[kt] = v;
      }
      f4v au0 = {0.f,0.f,0.f,0.f}, au1 = au0;
      f4v ag[4]; ag[0] = au0; ag[1] = au0; ag[2] = au0; ag[3] = au0;
      #pragma unroll
      for (int f = 0; f < 48; ++f) {
        s8v bcur = bnext;
        asm volatile("s_waitcnt vmcnt(4)" ::: "memory");
        __builtin_amdgcn_sched_barrier(0);
        bnext = *(const s8v*)(wslice + (((f + 1) % 6) * 16384));
        if (f < 8) {
          if (f & 1) au1 = mfma16(adc[f], bcur, au1);
          else       au0 = mfma16(adc[f], bcur, au0);
        } else if (f < 16) {
          s8v cv = (s8v)0;
          if (arOK) cv = *(const s8v*)(dcbase + f * 64);
          if (f & 1) au1 = mfma16(cv, bcur, au1);
          else       au0 = mfma16(cv, bcur, au0);
        } else {
          ag[(f - 16) >> 3] = mfma16(adc[f & 7], bcur, ag[(f - 16) >> 3]);
        }
        const int nf = (f + 6) % 48;
        __builtin_amdgcn_global_load_lds((const unsigned int*)(WPc + (size_t)nf * 16384 + wlo),
                                         (unsigned int*)(wdst + (f % 6) * 16384), 16, 0, 0);
      }
      f4v au = au0 + au1;
      #pragma unroll
      for (int r = 0; r < 4; ++r) au[r] += __shfl_xor(au[r], 16);
      #pragma unroll
      for (int r = 0; r < 4; ++r) {
        ag[r][0] += __shfl_xor(ag[r][0], 16);
        ag[r][1] += __shfl_xor(ag[r][1], 16);
        ag[r][2] += __shfl_xor(ag[r][2], 16);
        ag[r][3] += __shfl_xor(ag[r][3], 16);
      }
      if (lane < 16) {
        const int hp = w * 20 + lane;
        #pragma unroll
        for (int r = 0; r < 4; ++r)
          us_s[r][hp] = tanh_f(au[r]);
        #pragma unroll
        for (int ct = 0; ct < 4; ++ct) {
          const int g0 = (w * 4 + ct) * 16 + lane;
          #pragma unroll
          for (int r = 0; r < 4; ++r)
            gts[r][g0] = ag[ct][r];
        }
      }
    }
    barrier_lgkm();

    // ===== fused B+C: online-softmax scores + context accumulation in one sweep =====
    {
      const int bq = w >> 2;
      const int cc = lane & 15;
      const int g4 = lane >> 4;
      float tur[16], wr[16];
      #pragma unroll
      for (int e4 = 0; e4 < 4; ++e4) {
        f4v tv = *(const f4v*)&us_s[bq][cc * 20 + e4 * 4];
        f4v wv = *(const f4v*)&w2s[cc * 16 + e4 * 4];
        #pragma unroll
        for (int j = 0; j < 4; ++j) {
          tur[e4 * 4 + j] = tv[j];
          wr[e4 * 4 + j] = wv[j];
        }
      }
      const unsigned short* txb = &Tx[((size_t)(b0 + bq) * TT) * 256 + cc * 16];
      const unsigned short* xbb = USE_XB ? &Xbf[((size_t)(b0 + bq) * TT) * 256 + cc * 16] : nullptr;
      const float* xfb = &X[((size_t)(b0 + bq) * TT) * 256 + cc * 16];

      float mrun = -3.0e38f, Z = 0.f;
      float cacc[16];
      #pragma unroll
      for (int e = 0; e < 16; ++e) cacc[e] = 0.f;

      #pragma unroll
      for (int it = 0; it < 8; ++it) {
        const int tt = it * 16 + (w & 3) * 4 + g4;
        const int ttc = tt < 126 ? tt : 126;
        const unsigned short* p = txb + (size_t)ttc * 256;
        s8v xa = *(const s8v*)p;
        s8v xb = *(const s8v*)(p + 8);
        // X slice for this (tt, m=cc*16+e)
        float xv[16];
        if constexpr (USE_XB) {
          const unsigned short* q = xbb + (size_t)ttc * 256;
          u4v d0 = *(const u4v*)q;
          u4v d1 = *(const u4v*)(q + 8);
          #pragma unroll
          for (int j = 0; j < 4; ++j) {
            xv[2*j]     = u2f_lo(d0[j]);
            xv[2*j + 1] = u2f_hi(d0[j]);
            xv[8 + 2*j]     = u2f_lo(d1[j]);
            xv[8 + 2*j + 1] = u2f_hi(d1[j]);
          }
        } else {
          const float* q = xfb + (size_t)ttc * 256;
          #pragma unroll
          for (int j = 0; j < 4; ++j) {
            f4v d = *(const f4v*)(q + j * 4);
            xv[4*j] = d[0]; xv[4*j+1] = d[1]; xv[4*j+2] = d[2]; xv[4*j+3] = d[3];
          }
        }
        float acc = 0.f;
        #pragma unroll
        for (int e = 0; e < 8; ++e) {
          const float x = bf2f((unsigned short)xa[e]);
          acc = fmaf(wr[e] * (tur[e] + x), frcp(fmaf(tur[e], x, 1.f)), acc);
        }
        #pragma unroll
        for (int e = 0; e < 8; ++e) {
          const float x = bf2f((unsigned short)xb[e]);
          acc = fmaf(wr[8 + e] * (tur[8 + e] + x), frcp(fmaf(tur[8 + e], x, 1.f)), acc);
        }
        acc += __shfl_xor(acc, 1);
        acc += __shfl_xor(acc, 2);
        acc += __shfl_xor(acc, 4);
        acc += __shfl_xor(acc, 8);
        const float s = (tt < TT) ? acc : -3.0e38f;
        if (s > mrun) {               // group-uniform branch
          const float scale = fexp2((mrun - s) * L2E);
          Z *= scale;
          #pragma unroll
          for (int e = 0; e < 16; ++e) cacc[e] *= scale;
          mrun = s;
        }
        const float pexp = fexp2((s - mrun) * L2E);
        Z += pexp;
        #pragma unroll
        for (int e = 0; e < 16; ++e) cacc[e] = fmaf(pexp, xv[e], cacc[e]);
      }
      // combine 4 groups within the wave
      float m2 = __shfl_xor(mrun, 16); float Mw = fmaxf(mrun, m2);
      m2 = __shfl_xor(Mw, 32); Mw = fmaxf(Mw, m2);
      const float gsc = fexp2((mrun - Mw) * L2E);
      Z *= gsc;
      Z += __shfl_xor(Z, 16);
      Z += __shfl_xor(Z, 32);
      #pragma unroll
      for (int e = 0; e < 16; ++e) {
        float c = cacc[e] * gsc;
        c += __shfl_xor(c, 16);
        c += __shfl_xor(c, 32);
        cacc[e] = c;
      }
      if (lane < 16) {
        #pragma unroll
        for (int e = 0; e < 16; ++e)
          ctxp_s[w][lane * 16 + e] = f2bf(cacc[e]);
      }
      if (lane == 0) {
        MZ_s[bq][w & 3] = Mw;
        MZ_s[bq][4 + (w & 3)] = Z;
      }
    }
    barrier_lgkm();

    // ===== combine waves: ctx[bb][hq] =====
    {
      const float M0 = MZ_s[bb][0], M1 = MZ_s[bb][1], M2 = MZ_s[bb][2], M3 = MZ_s[bb][3];
      const float M = fmaxf(fmaxf(M0, M1), fmaxf(M2, M3));
      const float e0 = fexp2((M0 - M) * L2E), e1 = fexp2((M1 - M) * L2E);
      const float e2 = fexp2((M2 - M) * L2E), e3 = fexp2((M3 - M) * L2E);
      const float den = MZ_s[bb][4] * e0 + MZ_s[bb][5] * e1 + MZ_s[bb][6] * e2 + MZ_s[bb][7] * e3;
      float cv = bf2f(ctxp_s[bb * 4 + 0][hq]) * e0
               + bf2f(ctxp_s[bb * 4 + 1][hq]) * e1
               + bf2f(ctxp_s[bb * 4 + 2][hq]) * e2
               + bf2f(ctxp_s[bb * 4 + 3][hq]) * e3;
      ctx[bb][hq] = cv * frcp(den);
    }
    barrier_lgkm();

    // ================= D1: y_tilde (waves 0..3) =================
    if (w < 4) {
      float a = 0.f;
      #pragma unroll
      for (int j = 0; j < 4; ++j) {
        const int m = lane + (j << 6);
        a = fmaf(ctx[w][m], fcw_s[m], a);
      }
      #pragma unroll
      for (int m = 32; m; m >>= 1) a += __shfl_xor(a, m);
      if (lane == 0)
        ytil[w] = a + fcw_s[256] * yp_s[w][t] + fcb0;
    }
    barrier_lgkm();

    // ================= D2/D3: gates + LSTM pointwise =================
    {
      const float yt = ytil[bb];
      const float gi = gts[bb][hq]       + yt * wih_s[hq]       + bsum_s[hq];
      const float gf = gts[bb][hq + 256] + yt * wih_s[hq + 256] + bsum_s[hq + 256];
      const float gg = gts[bb][hq + 512] + yt * wih_s[hq + 512] + bsum_s[hq + 512];
      const float go = gts[bb][hq + 768] + yt * wih_s[hq + 768] + bsum_s[hq + 768];
      creg = sigm(gf) * creg + sigm(gi) * tanh_f(gg);
      dreg = sigm(go) * tanh_f(creg);
      const unsigned short dh = f2bf(dreg);
      const unsigned short dl = f2bf(dreg - bf2f(dh));
      const unsigned short ch = f2bf(creg);
      const unsigned short cl = f2bf(creg - bf2f(ch));
      dcA[bb][hq] = dh;           dcA[bb + 4][hq] = dl;
      dcA[bb][256 + hq] = ch;     dcA[bb + 4][256 + hq] = cl;
    }
    barrier_lgkm();
  }

  // ---- output: y_pred = [d, context]·fcfW^T + fcfb ----
  us_s[bb][hq] = dreg;
  barrier_lgkm();
  if (w < 4) {
    float a = 0.f;
    #pragma unroll
    for (int j = 0; j < 4; ++j) {
      const int m = lane + (j << 6);
      a = fmaf(us_s[w][m], fcfw_s[m], a);
      a = fmaf(ctx[w][m], fcfw_s[256 + m], a);
    }
    #pragma unroll
    for (int m = 32; m; m >>= 1) a += __shfl_xor(a, m);
    if (lane == 0) out[b0 + w] = a + fcfb0;
  }
  asm volatile("s_waitcnt vmcnt(0)" ::: "memory");
}

extern "C" void kernel_launch(void* const* d_in, const int* in_sizes, int n_in,
                              void* d_out, int out_size, void* d_ws, size_t ws_size,
                              hipStream_t stream) {
  const float* X    = (const float*)d_in[0];
  const float* yprev= (const float*)d_in[1];
  const float* W1   = (const float*)d_in[2];
  const float* b1   = (const float*)d_in[3];
  const float* W2   = (const float*)d_in[4];
  // d_in[5] = attn_b2: softmax-invariant, unused
  const float* Wih  = (const float*)d_in[6];
  const float* Whh  = (const float*)d_in[7];
  const float* bih  = (const float*)d_in[8];
  const float* bhh  = (const float*)d_in[9];
  const float* fcW  = (const float*)d_in[10];
  const float* fcb  = (const float*)d_in[11];
  const float* fcfW = (const float*)d_in[12];
  const float* fcfb = (const float*)d_in[13];
  float* out = (float*)d_out;

  size_t off = 0;
  char* base = (char*)d_ws;
  auto alloc = [&](size_t bytes) -> void* {
    void* p = base + off;
    off += (bytes + 255) & ~(size_t)255;
    return p;
  };
  const size_t txBytes = (size_t)1024 * TT * 256 * 2;
  unsigned short* Tx   = (unsigned short*)alloc(txBytes);
  unsigned short* WP   = (unsigned short*)alloc((size_t)48 * 16384);
  float* W1xT          = (float*)alloc((size_t)256 * 256 * 4);
  unsigned short* Xbf = nullptr;
  if (ws_size >= off + txBytes + 1024) Xbf = (unsigned short*)alloc(txBytes);
  (void)in_sizes; (void)n_in; (void)out_size;

  k_pack_w1dc<<<64, 256, 0, stream>>>(W1, WP);
  k_pack_whh<<<128, 256, 0, stream>>>(Whh, WP);
  k_tr_w1x<<<256, 256, 0, stream>>>(W1, W1xT);
  dim3 gg(2032, 4);
  k_gemm_tx<<<gg, 256, 0, stream>>>(X, W1xT, b1, Tx);
  if (Xbf) {
    k_xbf<<<32512, 256, 0, stream>>>(X, Xbf);
    k_main<1><<<256, 1024, 0, stream>>>(X, Tx, Xbf, WP, yprev, W2,
                                        Wih, bih, bhh, fcW, fcb, fcfW, fcfb, out);
  } else {
    k_main<0><<<256, 1024, 0, stream>>>(X, Tx, nullptr, WP, yprev, W2,
                                        Wih, bih, bhh, fcW, fcb, fcfW, fcfb, out);
  }
}